// Round 12
// baseline (129.075 us; speedup 1.0000x reference)
//
#include <hip/hip_runtime.h>
#include <hip/hip_bf16.h>
#include <cstdint>

typedef __bf16 bf16;
typedef __bf16 bf16x8 __attribute__((ext_vector_type(8)));
typedef float f32x4 __attribute__((ext_vector_type(4)));
typedef float f32x8 __attribute__((ext_vector_type(8)));
typedef float f32x16 __attribute__((ext_vector_type(16)));

#define DIM   1024
#define SEQ   2048
#define BATCH 2
#define HEADS 16
#define HDIM  64

// log2(e)/sqrt(HDIM) — folded into Q at the QKV-GEMM epilogue so the
// attention kernel computes p = exp2(score) directly.
#define QSCALE 0.1803368801111204f

__device__ __forceinline__ void gload_lds16(const void* g, void* l) {
    __builtin_amdgcn_global_load_lds(
        (const __attribute__((address_space(1))) void*)g,
        (__attribute__((address_space(3))) void*)l,
        16, 0, 0);
}

__device__ __forceinline__ uint32_t pkbf(float a, float b) {
    union { bf16 h[2]; uint32_t u; } t;
    t.h[0] = (bf16)a; t.h[1] = (bf16)b;
    return t.u;
}

#define LO8(v)  __builtin_shufflevector(v, v, 0, 1, 2, 3, 4, 5, 6, 7)
#define HI8(v)  __builtin_shufflevector(v, v, 8, 9, 10, 11, 12, 13, 14, 15)
#define LO4(v)  __builtin_shufflevector(v, v, 0, 1, 2, 3)
#define HI4(v)  __builtin_shufflevector(v, v, 4, 5, 6, 7)

// ------------- convert + transpose weights: W[K][N] -> Wt[N][K] bf16 -------------
__global__ __launch_bounds__(256) void cvt_wt_kernel(const float* __restrict__ Wq,
                                                     const float* __restrict__ Wk,
                                                     const float* __restrict__ Wv,
                                                     const float* __restrict__ Wo,
                                                     bf16* __restrict__ Wt) {
    int z = blockIdx.z;
    const float* W = (z == 0) ? Wq : (z == 1) ? Wk : (z == 2) ? Wv : Wo;
    bf16* out = Wt + (size_t)z * DIM * DIM;
    int w = threadIdx.x >> 6, lane = threadIdx.x & 63;
    int n  = blockIdx.x * 64 + lane;     // output row (orig col) — lane-contig reads
    int kb = blockIdx.y * 32 + w * 8;    // 8 consecutive k per thread
    bf16x8 o;
#pragma unroll
    for (int j = 0; j < 8; ++j)
        o[j] = (bf16)W[(size_t)(kb + j) * DIM + n];   // coalesced 256B per row
    *(bf16x8*)(out + (size_t)n * DIM + kb) = o;
}

// ---------------- 128x128-tile bf16 GEMM (m97 structure) ----------------
// Bt: N x K row-major bf16 (transposed weight).
// MODE 0: A = x, M x K row-major FP32 — converted to bf16 in-staging (fused
//         cvt_x).  z picks weight/bias/output.  Q out row-major (B*H,S,Dh),
//         pre-scaled by QSCALE.  K and V out in FRAGMENT-MAJOR layout: per
//         (head, 32-kv block) a 4 KB block of 4 x 1KB MFMA-operand chunks,
//         lane l owning bytes [16l,16l+16) — so attention reads operands as
//         single coalesced global_load_dwordx4, no LDS at all.
// MODE 1: A bf16; f32 row-major out + bias.
template <int MODE>
__global__ __launch_bounds__(256) void gemm128_kernel(
        const void* __restrict__ Ap,
        const bf16* __restrict__ WtB,
        const float* __restrict__ b0,
        const float* __restrict__ b1,
        const float* __restrict__ b2,
        void* __restrict__ outp) {
    constexpr int K = DIM;
    int z = (MODE == 0) ? blockIdx.z : 0;
    const bf16* Bt = WtB + (size_t)z * DIM * DIM;
    const float* bias = (MODE == 0) ? ((z == 0) ? b0 : (z == 1) ? b1 : b2) : b0;

    int m0 = blockIdx.y * 128, n0 = blockIdx.x * 128;
    int tid = threadIdx.x;
    int w = tid >> 6, lane = tid & 63, l15 = lane & 15, l4 = lane >> 4;
    int wr = (w >> 1) * 64, wc = (w & 1) * 64;

    __shared__ __align__(16) bf16 As[128 * 32];
    __shared__ __align__(16) bf16 Bs[128 * 32];

    // MODE 0 fused-cvt A staging: thread -> (row, 16-k half)
    int arow = tid >> 1, acol = (tid & 1) * 16;
    const float* asrc = (MODE == 0)
        ? (const float*)Ap + (size_t)(m0 + arow) * K + acol : nullptr;

    f32x4 acc[4][4] = {};

    for (int k0 = 0; k0 < K; k0 += 32) {
#pragma unroll
        for (int r = 0; r < 2; ++r) {
            int c = r * 256 + tid;   // 16B chunk id; lane-linear in LDS
            gload_lds16(Bt + (size_t)(n0 + (c >> 2)) * K + k0 + (c & 3) * 8, &Bs[c * 8]);
        }
        if constexpr (MODE == 0) {
            // A: read x f32 directly, convert, ds_write (fused cvt_x)
            const float4* s4 = (const float4*)(asrc + k0);
            float4 f0 = s4[0], f1 = s4[1], f2 = s4[2], f3 = s4[3];
            bf16x8 e0, e1;
            e0[0] = (bf16)f0.x; e0[1] = (bf16)f0.y; e0[2] = (bf16)f0.z; e0[3] = (bf16)f0.w;
            e0[4] = (bf16)f1.x; e0[5] = (bf16)f1.y; e0[6] = (bf16)f1.z; e0[7] = (bf16)f1.w;
            e1[0] = (bf16)f2.x; e1[1] = (bf16)f2.y; e1[2] = (bf16)f2.z; e1[3] = (bf16)f2.w;
            e1[4] = (bf16)f3.x; e1[5] = (bf16)f3.y; e1[6] = (bf16)f3.z; e1[7] = (bf16)f3.w;
            *(bf16x8*)&As[arow * 32 + acol]     = e0;
            *(bf16x8*)&As[arow * 32 + acol + 8] = e1;
        } else {
            const bf16* A = (const bf16*)Ap;
#pragma unroll
            for (int r = 0; r < 2; ++r) {
                int c = r * 256 + tid;
                gload_lds16(A + (size_t)(m0 + (c >> 2)) * K + k0 + (c & 3) * 8, &As[c * 8]);
            }
        }
        __syncthreads();
        bf16x8 af[4], bfr[4];
#pragma unroll
        for (int m = 0; m < 4; ++m)
            af[m] = *(const bf16x8*)&As[(wr + m * 16 + l15) * 32 + l4 * 8];
#pragma unroll
        for (int n = 0; n < 4; ++n)
            bfr[n] = *(const bf16x8*)&Bs[(wc + n * 16 + l15) * 32 + l4 * 8];
#pragma unroll
        for (int m = 0; m < 4; ++m)
#pragma unroll
            for (int n = 0; n < 4; ++n)
                acc[m][n] = __builtin_amdgcn_mfma_f32_16x16x32_bf16(
                    af[m], bfr[n], acc[m][n], 0, 0, 0);
        __syncthreads();
    }

    // epilogue: C/D layout col=lane&15, row=(lane>>4)*4+i  [m89-verified]
    float oscale = (MODE == 0 && z == 0) ? QSCALE : 1.0f;   // fold softmax scale into Q
#pragma unroll
    for (int n = 0; n < 4; ++n) {
        int col = n0 + wc + n * 16 + l15;
        float bv = bias[col];
#pragma unroll
        for (int m = 0; m < 4; ++m) {
            int rowb = m0 + wr + m * 16 + l4 * 4;
            if (MODE == 1) {
                float* out = (float*)outp;
#pragma unroll
                for (int i = 0; i < 4; ++i)
                    out[(size_t)(rowb + i) * DIM + col] = acc[m][n][i] + bv;
            } else if (z == 0) {   // Q: row-major (B*H, S, Dh), pre-scaled
                bf16* out = (bf16*)outp;
                int h = col >> 6, d = col & 63;
#pragma unroll
                for (int i = 0; i < 4; ++i) {
                    int row = rowb + i;
                    int bb = row >> 11, s = row & 2047;
                    out[(((size_t)(bb * HEADS + h)) * SEQ + s) * HDIM + d] =
                        (bf16)((acc[m][n][i] + bv) * oscale);
                }
            } else if (z == 1) {   // K: fragment-major A-operand layout
                char* out = (char*)outp + (size_t)(BATCH * HEADS * SEQ * HDIM) * 2;
                int h = col >> 6, d = col & 63;
                int ks = d >> 4, lbase = ((d >> 3) & 1) * 32, e = d & 7;
#pragma unroll
                for (int i = 0; i < 4; ++i) {
                    int row = rowb + i;
                    int bb = row >> 11, s = row & 2047;
                    int hb2 = bb * HEADS + h;
                    size_t off = (size_t)(hb2 * 64 + (s >> 5)) * 4096
                                 + ks * 1024 + ((s & 31) + lbase) * 16 + e * 2;
                    *(bf16*)(out + off) = (bf16)(acc[m][n][i] + bv);
                }
            } else {              // V: fragment-major V^T A-operand layout
                char* out = (char*)outp + (size_t)2 * (BATCH * HEADS * SEQ * HDIM) * 2;
                int h = col >> 6, d = col & 63;
                int dblk = d >> 5;
                int bb = rowb >> 11, s0 = rowb & 2047;
                int hb2 = bb * HEADS + h;
                int lane2 = (d & 31) + 32 * ((s0 >> 3) & 1);
                size_t off = (size_t)(hb2 * 64 + (s0 >> 5)) * 4096
                             + (dblk * 2 + ((s0 >> 4) & 1)) * 1024
                             + lane2 * 16 + (s0 & 7) * 2;
                union { bf16 hh[4]; ushort4 v; } pk;
#pragma unroll
                for (int i = 0; i < 4; ++i) pk.hh[i] = (bf16)(acc[m][n][i] + bv);
                *(ushort4*)(out + off) = pk.v;
            }
        }
    }
}

// --- flash attention: swapped-QK^T 32x32, no-max softmax, DIRECT fragment-major K/V ---
// R11 showed LDS-read pipe (8x wave redundancy + 4-way conflicts ~ 27us/CU)
// is the binder.  K/V now live in global in fragment-major layout (1 KB per
// MFMA operand, lane-linear) -> each fragment is ONE coalesced
// global_load_dwordx4 from L2 (R7's failure was scatter, not directness).
// No LDS, no barriers, no conflicts.  kv32 steps keep live state minimal;
// kv-split x2 (R8 exact-merge) gives 1024 blocks -> 4 blocks/CU; with
// __launch_bounds__(256,4) (VGPR<=128) -> 4 waves/SIMD latency hiding.
// Per-XCD L2 resident set = 4 heads x 512 KB = 2 MB (R11 affinity decode).
__global__ __launch_bounds__(256, 4) void attn_kernel(const bf16* __restrict__ Q,
                                                      const bf16* __restrict__ Kf,
                                                      const bf16* __restrict__ Vf,
                                                      bf16* __restrict__ opA,
                                                      bf16* __restrict__ opB,
                                                      float* __restrict__ lbuf) {
    // XCD-aware bijective decode [T1; 8 XCDs]: XCD k owns heads 4k..4k+3
    int bid = blockIdx.x;                 // 0..1023
    int xcd = bid & 7, i = bid >> 3;      // 128 blocks per XCD
    int hb  = xcd * 4 + (i >> 5);
    int rem = i & 31;
    int q0  = (rem >> 1) * 128;
    int si  = rem & 1;                    // KV split index
    int bb = hb >> 4, h = hb & 15;
    int tid = threadIdx.x, w = tid >> 6, lane = tid & 63;
    int l31 = lane & 31, hi = lane >> 5;

    const bf16* Qh = Q + (size_t)hb * SEQ * HDIM;
    const char* kj = (const char*)Kf + (size_t)(hb * 64 + si * 32) * 4096 + lane * 16;
    const char* vj = (const char*)Vf + (size_t)(hb * 64 + si * 32) * 4096 + lane * 16;

    // Q as B-operand frags: col = q = l31, k(dh) = 16*ks + 8*hi + e
    int qrow = q0 + w * 32 + l31;
    bf16x8 qf[4];
#pragma unroll
    for (int ks = 0; ks < 4; ++ks)
        qf[ks] = *(const bf16x8*)&Qh[(size_t)qrow * HDIM + ks * 16 + hi * 8];

    f32x16 o0 = {}, o1 = {};
    float l = 0.f;                      // lane-local partial denominator

    for (int j = 0; j < 32; ++j) {      // 32 kv-blocks of 32 per split half
        // coalesced operand loads: 8 x 1KB (lane l reads its own 16 B)
        bf16x8 k0 = *(const bf16x8*)(kj);
        bf16x8 k1 = *(const bf16x8*)(kj + 1024);
        bf16x8 k2 = *(const bf16x8*)(kj + 2048);
        bf16x8 k3 = *(const bf16x8*)(kj + 3072);
        bf16x8 v0 = *(const bf16x8*)(vj);
        bf16x8 v1 = *(const bf16x8*)(vj + 1024);
        bf16x8 v2 = *(const bf16x8*)(vj + 2048);
        bf16x8 v3 = *(const bf16x8*)(vj + 3072);
        kj += 4096; vj += 4096;

        // S^T = K(A) * Q^T(B): 32 kv rows (crow over regs), cols = q (lane&31)
        f32x16 s0 = {};
        __builtin_amdgcn_s_setprio(1);
        s0 = __builtin_amdgcn_mfma_f32_32x32x16_bf16(k0, qf[0], s0, 0, 0, 0);
        s0 = __builtin_amdgcn_mfma_f32_32x32x16_bf16(k1, qf[1], s0, 0, 0, 0);
        s0 = __builtin_amdgcn_mfma_f32_32x32x16_bf16(k2, qf[2], s0, 0, 0, 0);
        s0 = __builtin_amdgcn_mfma_f32_32x32x16_bf16(k3, qf[3], s0, 0, 0, 0);
        __builtin_amdgcn_s_setprio(0);

        // p = exp2(s) (scale folded into Q; softmax shift-invariant, no max)
#pragma unroll
        for (int r = 0; r < 16; ++r)
            s0[r] = __builtin_amdgcn_exp2f(s0[r]);

        // lane-local partial sum (cross-half merge deferred to the end)
        f32x8 a8 = LO8(s0) + HI8(s0);
        f32x4 a4 = LO4(a8) + HI4(a8);
        l += (a4[0] + a4[1]) + (a4[2] + a4[3]);

        // P (16 f32/lane) -> 2 bf16x8 PV B-frags: 8 cvt_pk + 4 permlane32_swap
        // (R2/R5-proven construction, rb=0 and rb=8 halves of s0)
        bf16x8 pa0, pa1;
        {
            uint32_t w0 = pkbf(s0[0], s0[1]), w1 = pkbf(s0[2], s0[3]);
            uint32_t w2 = pkbf(s0[4], s0[5]), w3 = pkbf(s0[6], s0[7]);
            asm("v_permlane32_swap_b32 %0, %1" : "+v"(w0), "+v"(w2));
            asm("v_permlane32_swap_b32 %0, %1" : "+v"(w1), "+v"(w3));
            union { uint32_t u[4]; bf16x8 v; } t2;
            t2.u[0] = w0; t2.u[1] = w1; t2.u[2] = w2; t2.u[3] = w3;
            pa0 = t2.v;
            uint32_t u0 = pkbf(s0[8], s0[9]),   u1 = pkbf(s0[10], s0[11]);
            uint32_t u2 = pkbf(s0[12], s0[13]), u3 = pkbf(s0[14], s0[15]);
            asm("v_permlane32_swap_b32 %0, %1" : "+v"(u0), "+v"(u2));
            asm("v_permlane32_swap_b32 %0, %1" : "+v"(u1), "+v"(u3));
            union { uint32_t u[4]; bf16x8 v; } t3;
            t3.u[0] = u0; t3.u[1] = u1; t3.u[2] = u2; t3.u[3] = u3;
            pa1 = t3.v;
        }

        // O^T += V^T(A) * P^T(B): rows = dh (crow), cols = q (lane&31)
        __builtin_amdgcn_s_setprio(1);
        o0 = __builtin_amdgcn_mfma_f32_32x32x16_bf16(v0, pa0, o0, 0, 0, 0);
        o0 = __builtin_amdgcn_mfma_f32_32x32x16_bf16(v1, pa1, o0, 0, 0, 0);
        o1 = __builtin_amdgcn_mfma_f32_32x32x16_bf16(v2, pa0, o1, 0, 0, 0);
        o1 = __builtin_amdgcn_mfma_f32_32x32x16_bf16(v3, pa1, o1, 0, 0, 0);
        __builtin_amdgcn_s_setprio(0);
    }

    // merge the two hi-half partials once; write bf16 o-partial + f32 l-partial
    l += __shfl_xor(l, 32);
    bf16* op = si ? opB : opA;
    if (hi == 0)
        lbuf[((size_t)si * BATCH * HEADS + hb) * SEQ + qrow] = l;
    size_t base = ((size_t)bb * SEQ + qrow) * DIM + h * HDIM;
#pragma unroll
    for (int g = 0; g < 4; ++g) {
        int dh0 = 8 * g + 4 * hi;
        union { bf16 hh[4]; ushort4 u; } a, b2;
#pragma unroll
        for (int i = 0; i < 4; ++i) {
            a.hh[i]  = (bf16)o0[4 * g + i];
            b2.hh[i] = (bf16)o1[4 * g + i];
        }
        *(ushort4*)&op[base + dh0]      = a.u;
        *(ushort4*)&op[base + 32 + dh0] = b2.u;
    }
}

// ---------- merge: ctx = (oA + oB) / (lA + lB), elementwise, 8 bf16/thread ----------
// opA aliases ctx (in-place elementwise safe: each thread touches only its 8 elems)
__global__ __launch_bounds__(256) void merge_kernel(const bf16* __restrict__ opA,
                                                    const bf16* __restrict__ opB,
                                                    const float* __restrict__ lbuf,
                                                    bf16* __restrict__ ctx) {
    int idx = blockIdx.x * 256 + threadIdx.x;
    size_t e8 = (size_t)idx * 8;
    int row = (int)(e8 >> 10);          // 0..4095 = bb*2048+s
    int d   = (int)(e8 & 1023);
    int h = d >> 6;
    int bb = row >> 11, s = row & 2047;
    int hb = bb * HEADS + h;
    float la = lbuf[(size_t)hb * SEQ + s];
    float lb = lbuf[((size_t)BATCH * HEADS + hb) * SEQ + s];
    float inv = 1.0f / (la + lb);
    bf16x8 a = *(const bf16x8*)&opA[e8];
    bf16x8 b = *(const bf16x8*)&opB[e8];
    bf16x8 o;
#pragma unroll
    for (int i = 0; i < 8; ++i)
        o[i] = (bf16)(((float)a[i] + (float)b[i]) * inv);
    *(bf16x8*)&ctx[e8] = o;
}

extern "C" void kernel_launch(void* const* d_in, const int* in_sizes, int n_in,
                              void* d_out, int out_size, void* d_ws, size_t ws_size,
                              hipStream_t stream) {
    const float* x  = (const float*)d_in[0];
    const float* Wq = (const float*)d_in[1];
    const float* bq = (const float*)d_in[2];
    const float* Wk = (const float*)d_in[3];
    const float* bk = (const float*)d_in[4];
    const float* Wv = (const float*)d_in[5];
    const float* bv = (const float*)d_in[6];
    const float* Wo = (const float*)d_in[7];
    const float* bo = (const float*)d_in[8];

    char* ws = (char*)d_ws;
    bf16* Wt  = (bf16*)(ws + (8u  << 20));          //  8 MiB: W^T bf16
    bf16* Qb  = (bf16*)(ws + (16u << 20));          //  8 MiB: Q (B*H,S,Dh), pre-scaled
    bf16* Kf  = (bf16*)(ws + (24u << 20));          //  8 MiB: K fragment-major
    bf16* Vf  = (bf16*)(ws + (32u << 20));          //  8 MiB: V fragment-major
    bf16* ctx = (bf16*)(ws + (40u << 20));          //  8 MiB: ctx (B,S,D)

    // attn partials reuse dead regions: o-partial A -> ctx (merged in-place),
    // o-partial B -> ws[0..8M) (free: cvt_x is fused), l-partials -> Wq^T region.
    bf16*  opA  = ctx;
    bf16*  opB  = (bf16*)ws;
    float* lbuf = (float*)Wt;

    cvt_wt_kernel<<<dim3(16, 32, 4), 256, 0, stream>>>(Wq, Wk, Wv, Wo, Wt);
    gemm128_kernel<0><<<dim3(8, 32, 3), 256, 0, stream>>>(x, Wt, bq, bk, bv, (void*)Qb);
    attn_kernel<<<1024, 256, 0, stream>>>(Qb, Kf, Vf, opA, opB, lbuf);
    merge_kernel<<<2048, 256, 0, stream>>>(opA, opB, lbuf, ctx);
    gemm128_kernel<1><<<dim3(8, 32, 1), 256, 0, stream>>>(
        ctx, Wt + (size_t)3 * DIM * DIM, bo, bo, bo, (void*)d_out);
}